// Round 15
// baseline (5688.356 us; speedup 1.0000x reference)
//
#include <hip/hip_runtime.h>

// PointNet++ SA module: FPS -> ball query (K nearest within R) -> gather ->
// 3-layer MLP -> masked max aggregation.
//
// B=4 batches, NP=8192 pts, MP=2048 centers/batch, K=64, R=0.2, D_IN=32.
// d_out = [x_out (8192*128) | pos_out (8192*3) | batch_out (8192)] as fp32.
//
// ws layout (bytes): flags only (1024 ints).
//   prog mirror m of batch b : flags[(b*8+m)*16]   (32 lines, 64B apart)
//   ticket of batch b        : flags[512 + b*16]
//
// Round-15: unlock worker registers.  r14's counters showed VGPR_Count=60
// while the worker path keeps h1[64]+acc[32] live (>=110 regs) -> hipcc was
// SPILLING h1 to scratch; every h1 read in the streaming-h2 loop was a
// scratch round-trip.  That is r13's measured anomaly (177K cyc/center vs
// the ~74K instruction floor).  At 1 block/CU (forced by 96KB LDS) a wave
// may use up to 512 VGPRs: __launch_bounds__(1024, 4) (4 waves/EU == 1
// block/CU) lifts the cap at zero occupancy cost.  With registers unlocked,
// the worker MLP returns to the r7-verified full-register form: h2[64]
// materialized ONCE (loop-order swapped so W2 is read row-contiguous -> no
// W2T), layer 3 in 2 passes x acc[64].  Worker FMA/center 24.5K -> 12.3K.

#define BATCH 4
#define NP 8192
#define MP 2048
#define KNN 64
#define DIN 32
#define NWORK 168
#define NBLK (BATCH + NWORK)
#define CAND_CAP 512   // max real candidate count ~360 (measured r2-r14)

// One v_max_f32 + DPP step (r2-verified: plain fmaxf; asm variants regressed).
#define DPP_FMAX(v, ctrl)                                                     \
  {                                                                           \
    int _t = __builtin_amdgcn_update_dpp(__float_as_int(v),                   \
                                         __float_as_int(v), (ctrl), 0xF,      \
                                         0xF, false);                         \
    (v) = fmaxf((v), __int_as_float(_t));                                     \
  }

// One v_min_u32 + DPP step (integer: no canonicalization exists).
#define DPP_MINU(v, ctrl)                                                     \
  {                                                                           \
    unsigned _t = (unsigned)__builtin_amdgcn_update_dpp((int)(v), (int)(v),   \
                                                        (ctrl), 0xF, 0xF,    \
                                                        false);               \
    (v) = ((v) < _t) ? (v) : _t;                                              \
  }

#define DPP_WAVEMAX6(v)                                                       \
  {                                                                           \
    DPP_FMAX(v, 0x111); DPP_FMAX(v, 0x112); DPP_FMAX(v, 0x114);               \
    DPP_FMAX(v, 0x118); DPP_FMAX(v, 0x142); DPP_FMAX(v, 0x143);               \
  }

#define DPP_WAVEMINU6(v)                                                      \
  {                                                                           \
    DPP_MINU(v, 0x111); DPP_MINU(v, 0x112); DPP_MINU(v, 0x114);               \
    DPP_MINU(v, 0x118); DPP_MINU(v, 0x142); DPP_MINU(v, 0x143);               \
  }

typedef float v2f __attribute__((ext_vector_type(2)));

// Relaxed agent-scope atomics: bypass the non-coherent per-XCD L2s, served
// at the LLC coherence point.  NO fences attached (r9/r10-verified).
__device__ __forceinline__ int aload(const int* p) {
  return __hip_atomic_load(p, __ATOMIC_RELAXED, __HIP_MEMORY_SCOPE_AGENT);
}
__device__ __forceinline__ void astore_i(int* p, int v) {
  __hip_atomic_store(p, v, __ATOMIC_RELAXED, __HIP_MEMORY_SCOPE_AGENT);
}
__device__ __forceinline__ float afload(const float* p) {
  return __hip_atomic_load(p, __ATOMIC_RELAXED, __HIP_MEMORY_SCOPE_AGENT);
}
__device__ __forceinline__ void afstore(float* p, float v) {
  __hip_atomic_store(p, v, __ATOMIC_RELAXED, __HIP_MEMORY_SCOPE_AGENT);
}

// ---------------------------------------------------------------- init -----
__global__ __launch_bounds__(1024) void init_k(int* __restrict__ flags) {
  flags[threadIdx.x] = 0;
}

// ---------------------------------------------------------------- mega -----
// (1024, 4): 4 waves/EU == exactly 1 block/CU (already forced by 96KB LDS).
// This lifts the VGPR cap to 512/wave so the worker MLP never spills.
__global__ __launch_bounds__(1024, 4) void mega_k(
    const float* __restrict__ pos, const float* __restrict__ x,
    const float* __restrict__ W1, const float* __restrict__ b1,
    const float* __restrict__ W2, const float* __restrict__ b2,
    const float* __restrict__ W3, const float* __restrict__ b3,
    float* __restrict__ pout, float* __restrict__ bout,
    float* __restrict__ xout, int* __restrict__ flags)
{
  // 98304B: fps ptab (96KB) / worker cand regions (16 x 512 u64 = 64KB)
  __shared__ __align__(16) float smem[NP * 3];
  __shared__ unsigned long long slt[2][16];
  __shared__ int hist[16];                 // winner idx of rows i-15..i

  const int bid = blockIdx.x;
  const int tid = threadIdx.x;
  const int lane = tid & 63, wid = tid >> 6;

  int b;
  if (bid < BATCH) {
    // ===================== FPS (r2/r6-verified, 16 waves) =================
    b = bid;
    float* const ptab = smem;
    const float* __restrict__ pb = pos + (size_t)b * NP * 3;
    const int base = tid * 8;

    bout[b * MP + tid] = (float)b;
    bout[b * MP + 1024 + tid] = (float)b;

    // load 8 points; stage into LDS table; unpack to registers
    float t[24];
    const float4* __restrict__ pv = (const float4*)(pb + (size_t)tid * 24);
#pragma unroll
    for (int q = 0; q < 6; q++) *(float4*)&t[q * 4] = pv[q];
#pragma unroll
    for (int q = 0; q < 6; q++)
      *(float4*)&ptab[tid * 24 + q * 4] = *(float4*)&t[q * 4];

    v2f px[4], py[4], pz[4], d[4];
#pragma unroll
    for (int j = 0; j < 4; j++) {
      px[j].x = t[6 * j + 0]; py[j].x = t[6 * j + 1]; pz[j].x = t[6 * j + 2];
      px[j].y = t[6 * j + 3]; py[j].y = t[6 * j + 4]; pz[j].y = t[6 * j + 5];
    }

    const float c0x = pb[0], c0y = pb[1], c0z = pb[2];
    if (tid == 0) hist[0] = 0;   // row 0 selects point 0 (flushed later)

    // initial distances to center 0 (same per-element expression as verified)
    float bv = -1.f;
    {
      v2f cx = {c0x, c0x}, cy = {c0y, c0y}, cz = {c0z, c0z};
#pragma unroll
      for (int j = 0; j < 4; j++) {
        v2f dx = px[j] - cx, dy = py[j] - cy, dz = pz[j] - cz;
        v2f nd = dx * dx + dy * dy + dz * dz;
        d[j] = nd;
        bv = fmaxf(bv, fmaxf(nd.x, nd.y));
      }
    }

    for (int i = 1; i < MP; i++) {
      float v = bv;
      DPP_WAVEMAX6(v);
      const float wmax =
          __int_as_float(__builtin_amdgcn_readlane(__float_as_int(v), 63));

      const unsigned long long m = __ballot(bv == wmax);
      const int src = (int)__builtin_ctzll(m);
      const int p = i & 1;
      if (lane == src) {
        int ks = 7;
#pragma unroll
        for (int k = 6; k >= 0; k--) {
          float dv = (k & 1) ? d[k >> 1].y : d[k >> 1].x;
          if (dv == wmax) ks = k;
        }
        slt[p][wid] = ((unsigned long long)__float_as_uint(wmax) << 32)
                      | (unsigned)(base + ks);
      }
      __syncthreads();

      const unsigned long long kv = slt[p][lane & 15];
      const float v2 = __uint_as_float((unsigned)(kv >> 32));
      float v2r = v2;
      DPP_FMAX(v2r, 0x111);
      DPP_FMAX(v2r, 0x112);
      DPP_FMAX(v2r, 0x114);
      DPP_FMAX(v2r, 0x118);
      const float mv =
          __int_as_float(__builtin_amdgcn_readlane(__float_as_int(v2r), 15));
      const unsigned long long m2 = __ballot(v2 == mv);
      const int mw = (int)__builtin_ctzll(m2);
      const int js = __builtin_amdgcn_readlane((int)(unsigned)kv, mw);
      const float ncx = ptab[js * 3 + 0];
      const float ncy = ptab[js * 3 + 1];
      const float ncz = ptab[js * 3 + 2];

      // record winner; batched flush every 16 iters keeps the per-iter loop
      // free of global stores.  Publish lags one window (already drained).
      if (tid == 0) hist[i & 15] = js;
      if ((i & 15) == 15 && wid == 0) {
        asm volatile("s_waitcnt vmcnt(0)" ::: "memory");
        if (lane < 8) astore_i(&flags[(b * 8 + lane) * 16], i - 15);
        if (lane < 16) {
          const int r = i - 15 + lane;           // (r & 15) == lane
          const int jj = hist[lane];
          afstore(&pout[((size_t)b * MP + r) * 3 + 0], ptab[jj * 3 + 0]);
          afstore(&pout[((size_t)b * MP + r) * 3 + 1], ptab[jj * 3 + 1]);
          afstore(&pout[((size_t)b * MP + r) * 3 + 2], ptab[jj * 3 + 2]);
        }
      }

      const v2f cx = {ncx, ncx}, cy = {ncy, ncy}, cz = {ncz, ncz};
      bv = -1.f;
#pragma unroll
      for (int j = 0; j < 4; j++) {
        v2f dx = px[j] - cx, dy = py[j] - cy, dz = pz[j] - cz;
        v2f nd = dx * dx + dy * dy + dz * dz;
        v2f dn;
        dn.x = fminf(d[j].x, nd.x);
        dn.y = fminf(d[j].y, nd.y);
        d[j] = dn;
        bv = fmaxf(bv, fmaxf(dn.x, dn.y));
      }
    }
    if (tid < 8) {     // final publish to all mirrors (last flush drained)
      asm volatile("s_waitcnt vmcnt(0)" ::: "memory");
      astore_i(&flags[(b * 8 + tid) * 16], MP);
    }
    __syncthreads();   // ptab dead; smem becomes worker cand regions
    // fall through: fps waves join the worker pool for their own batch
  } else {
    b = (bid - BATCH) & 3;
  }

  // ======================= WORKERS (168 blocks + 4 fps blocks) ==========
  // Each block polls its own progress MIRROR (8 per batch, 64B-line each).
  // Gap-proportional sleep (production rate ~1 row/us known).
  int* const myprog = &flags[(b * 8 + ((bid >> 2) & 7)) * 16];
  int* const tk     = &flags[512 + b * 16];
  unsigned long long* const cw =
      (unsigned long long*)smem + (size_t)wid * CAND_CAP;
  const float R2 = (float)(0.2 * 0.2);
  const float* __restrict__ pb = pos + (size_t)b * NP * 3;

  for (;;) {
    int t;
    if (lane == 0) t = atomicAdd(tk, 1);
    t = __builtin_amdgcn_readfirstlane(t);
    if (t >= MP) break;
    const int cIdx = t;
    const int wg = b * MP + cIdx;

    for (;;) {
      const int pr = aload(myprog);
      const int g = cIdx + 1 - pr;
      if (g <= 0) break;
      if (g > 128) {
        __builtin_amdgcn_s_sleep(127);
        __builtin_amdgcn_s_sleep(127);
        __builtin_amdgcn_s_sleep(127);
      } else if (g > 16) {
        __builtin_amdgcn_s_sleep(127);
      } else {
        __builtin_amdgcn_s_sleep(16);
      }
    }
    // coords read uncached from the LLC — producer drained its coord
    // stores before publishing (16-row lag).  No fence needed.
    const float cx = afload(&pout[(size_t)wg * 3 + 0]);
    const float cy = afload(&pout[(size_t)wg * 3 + 1]);
    const float cz = afload(&pout[(size_t)wg * 3 + 2]);

    // ---- ball query: compaction (r7-verified) ----
    int cnt = 0;
    for (int basej = 0; basej < NP; basej += 64) {
      const int j = basej + lane;
      float dx = pb[j * 3 + 0] - cx;
      float dy = pb[j * 3 + 1] - cy;
      float dz = pb[j * 3 + 2] - cz;
      float d2 = dx * dx + dy * dy + dz * dz;
      bool in = (d2 <= R2);
      unsigned long long mb = __ballot(in);
      int pre = (int)__popcll(mb & ((1ull << lane) - 1ull));
      int slot = cnt + pre;
      if (in && slot < CAND_CAP)
        cw[slot] = ((unsigned long long)__float_as_uint(d2) << 32)
                   | (unsigned int)j;
      cnt += (int)__popcll(mb);
    }
    if (cnt > CAND_CAP) cnt = CAND_CAP;  // unreachable (max ~360)

    // ---- KNN selection: threshold scan + DPP argmin (r7-verified) ----
    unsigned long long last = 0;
    int myout = -1;
    for (int r = 0; r < KNN; r++) {
      unsigned long long v = ~0ull;
      for (int s = lane; s < cnt; s += 64) {
        const unsigned long long c = cw[s];
        if (c >= last && c < v) v = c;
      }
      const unsigned hi = (unsigned)(v >> 32);
      unsigned h = hi;
      DPP_WAVEMINU6(h);
      const unsigned mhi = (unsigned)__builtin_amdgcn_readlane((int)h, 63);
      const unsigned lo = (hi == mhi) ? (unsigned)v : 0xffffffffu;
      unsigned l2 = lo;
      DPP_WAVEMINU6(l2);
      const unsigned mlo = (unsigned)__builtin_amdgcn_readlane((int)l2, 63);
      if (lane == r) myout = (mhi == 0xffffffffu) ? -1 : (int)mlo;
      last = (mhi == 0xffffffffu)
                 ? ~0ull
                 : ((((unsigned long long)mhi << 32) | mlo) + 1ull);
    }

    // ---- MLP + max: full-register (no spill at VGPR cap 512) ----
    const int idx = myout;
    const bool valid = idx >= 0;
    const int j = valid ? idx : 0;
    const float* __restrict__ pj = pos + ((size_t)b * NP + j) * 3;
    const float rx = pj[0] - cx, ry = pj[1] - cy, rz = pj[2] - cz;

    // layer 1: h1 = relu(x @ W1[0:32] + rel @ W1[32:35] + b1)
    float h1[64];
#pragma unroll
    for (int k = 0; k < 64; k++) h1[k] = 0.f;
    {
      const float* __restrict__ xr = x + ((size_t)b * NP + j) * DIN;
#pragma unroll
      for (int half = 0; half < 2; half++) {
        float xv[16];
#pragma unroll
        for (int q = 0; q < 4; q++)
          *(float4*)&xv[q * 4] = ((const float4*)xr)[half * 4 + q];
#pragma unroll
        for (int c = 0; c < 16; c++) {
          const float xc = xv[c];
          const float* __restrict__ w = W1 + (half * 16 + c) * 64;
#pragma unroll
          for (int k = 0; k < 64; k++) h1[k] += xc * w[k];
        }
      }
    }
#pragma unroll
    for (int k = 0; k < 64; k++) {
      float vv = h1[k] + rx * W1[32 * 64 + k] + ry * W1[33 * 64 + k]
                       + rz * W1[34 * 64 + k] + b1[k];
      h1[k] = fmaxf(vv, 0.f);
    }

    // layer 2: h2 = relu(h1 @ W2 + b2), accumulated over k so W2 is read
    // row-contiguous (wide wave-uniform s_loads; no transpose buffer)
    float h2[64];
#pragma unroll
    for (int c = 0; c < 64; c++) h2[c] = b2[c];
#pragma unroll
    for (int k = 0; k < 64; k++) {
      const float hk = h1[k];
      const float* __restrict__ w = W2 + k * 64;
#pragma unroll
      for (int c = 0; c < 64; c++) h2[c] += hk * w[c];
    }
#pragma unroll
    for (int c = 0; c < 64; c++) h2[c] = fmaxf(h2[c], 0.f);
    // h1 dead from here -> registers free for acc[64]

    // layer 3 in 2 passes x 64 channels; W3 rows contiguous per c
    float4 keep = make_float4(0.f, 0.f, 0.f, 0.f);
    for (int pass = 0; pass < 2; pass++) {
      float acc[64];
#pragma unroll
      for (int g = 0; g < 64; g++) acc[g] = b3[pass * 64 + g];
#pragma unroll
      for (int c = 0; c < 64; c++) {
        const float h2c = h2[c];
        const float* __restrict__ w3r = W3 + c * 128 + pass * 64;
#pragma unroll
        for (int g = 0; g < 64; g++) acc[g] += h2c * w3r[g];
      }
#pragma unroll
      for (int g4 = 0; g4 < 16; g4++) {
        float a0 = valid ? fmaxf(acc[g4 * 4 + 0], 0.f) : 0.f;
        float a1 = valid ? fmaxf(acc[g4 * 4 + 1], 0.f) : 0.f;
        float a2 = valid ? fmaxf(acc[g4 * 4 + 2], 0.f) : 0.f;
        float a3 = valid ? fmaxf(acc[g4 * 4 + 3], 0.f) : 0.f;
        DPP_WAVEMAX6(a0);
        DPP_WAVEMAX6(a1);
        DPP_WAVEMAX6(a2);
        DPP_WAVEMAX6(a3);
        const float m0 =
            __int_as_float(__builtin_amdgcn_readlane(__float_as_int(a0), 63));
        const float m1 =
            __int_as_float(__builtin_amdgcn_readlane(__float_as_int(a1), 63));
        const float m2 =
            __int_as_float(__builtin_amdgcn_readlane(__float_as_int(a2), 63));
        const float m3 =
            __int_as_float(__builtin_amdgcn_readlane(__float_as_int(a3), 63));
        if (lane == pass * 16 + g4) {
          keep.x = m0; keep.y = m1; keep.z = m2; keep.w = m3;
        }
      }
    }
    if (lane < 32)
      *(float4*)&xout[(size_t)wg * 128 + lane * 4] = keep;
  }
}

// --------------------------------------------------------------- launch ----
extern "C" void kernel_launch(void* const* d_in, const int* in_sizes, int n_in,
                              void* d_out, int out_size, void* d_ws, size_t ws_size,
                              hipStream_t stream)
{
  const float* x   = (const float*)d_in[0];
  const float* pos = (const float*)d_in[1];
  // d_in[2] = batch (unused; layout is implicit)
  const float* W1 = (const float*)d_in[3];
  const float* b1 = (const float*)d_in[4];
  const float* W2 = (const float*)d_in[5];
  const float* b2 = (const float*)d_in[6];
  const float* W3 = (const float*)d_in[7];
  const float* b3 = (const float*)d_in[8];

  float* out  = (float*)d_out;
  float* xout = out;                          // 8192*128
  float* pout = out + 8192 * 128;             // 8192*3
  float* bout = out + 8192 * 128 + 8192 * 3;  // 8192

  int* flags = (int*)d_ws;                    // 1024 ints

  init_k<<<dim3(1), dim3(1024), 0, stream>>>(flags);
  mega_k<<<dim3(NBLK), dim3(1024), 0, stream>>>(pos, x, W1, b1, W2, b2, W3,
                                                b3, pout, bout, xout, flags);
}

// Round 16
// 2255.380 us; speedup vs baseline: 2.5221x; 2.5221x over previous
//
#include <hip/hip_runtime.h>

// PointNet++ SA module: FPS -> ball query (K nearest within R) -> gather ->
// 3-layer MLP -> masked max aggregation.
//
// B=4 batches, NP=8192 pts, MP=2048 centers/batch, K=64, R=0.2, D_IN=32.
// d_out = [x_out (8192*128) | pos_out (8192*3) | batch_out (8192)] as fp32.
//
// ws layout (bytes): flags only (1024 ints).
//   prog mirror m of batch b : flags[(b*8+m)*16]   (32 lines, 64B apart)
//   ticket of batch b        : flags[512 + b*16]
//
// Round-16: r14 byte-frozen + __launch_bounds__(1024, 4).  r15's failure:
// (1024,4) caps VGPR at 512/4 = 128/wave, and the full-register MLP needed
// ~190 -> wholesale array spill (FETCH 6.9GB of scratch).  r14's STREAMING
// worker form (h1[64] + acc[32] + temps ~= 106 live) FITS under 128 — r14
// ran it at VGPR_Count=60 (no min-waves hint -> conservative allocator) and
// spilled h1, which is r13's measured 177K-vs-74K cyc/center anomaly.  This
// round: streaming form + the 128-cap hint => no spill, h1 reads become
// register reads, worker per-center cost ~177K -> ~70-90K cyc.

#define BATCH 4
#define NP 8192
#define MP 2048
#define KNN 64
#define DIN 32
#define NWORK 168
#define NBLK (BATCH + NWORK)
#define CAND_CAP 512   // max real candidate count ~360 (measured r2-r15)

// One v_max_f32 + DPP step (r2-verified: plain fmaxf; asm variants regressed).
#define DPP_FMAX(v, ctrl)                                                     \
  {                                                                           \
    int _t = __builtin_amdgcn_update_dpp(__float_as_int(v),                   \
                                         __float_as_int(v), (ctrl), 0xF,      \
                                         0xF, false);                         \
    (v) = fmaxf((v), __int_as_float(_t));                                     \
  }

// One v_min_u32 + DPP step (integer: no canonicalization exists).
#define DPP_MINU(v, ctrl)                                                     \
  {                                                                           \
    unsigned _t = (unsigned)__builtin_amdgcn_update_dpp((int)(v), (int)(v),   \
                                                        (ctrl), 0xF, 0xF,    \
                                                        false);               \
    (v) = ((v) < _t) ? (v) : _t;                                              \
  }

#define DPP_WAVEMAX6(v)                                                       \
  {                                                                           \
    DPP_FMAX(v, 0x111); DPP_FMAX(v, 0x112); DPP_FMAX(v, 0x114);               \
    DPP_FMAX(v, 0x118); DPP_FMAX(v, 0x142); DPP_FMAX(v, 0x143);               \
  }

#define DPP_WAVEMINU6(v)                                                      \
  {                                                                           \
    DPP_MINU(v, 0x111); DPP_MINU(v, 0x112); DPP_MINU(v, 0x114);               \
    DPP_MINU(v, 0x118); DPP_MINU(v, 0x142); DPP_MINU(v, 0x143);               \
  }

typedef float v2f __attribute__((ext_vector_type(2)));

// Relaxed agent-scope atomics: bypass the non-coherent per-XCD L2s, served
// at the LLC coherence point.  NO fences attached (r9/r10-verified).
__device__ __forceinline__ int aload(const int* p) {
  return __hip_atomic_load(p, __ATOMIC_RELAXED, __HIP_MEMORY_SCOPE_AGENT);
}
__device__ __forceinline__ void astore_i(int* p, int v) {
  __hip_atomic_store(p, v, __ATOMIC_RELAXED, __HIP_MEMORY_SCOPE_AGENT);
}
__device__ __forceinline__ float afload(const float* p) {
  return __hip_atomic_load(p, __ATOMIC_RELAXED, __HIP_MEMORY_SCOPE_AGENT);
}
__device__ __forceinline__ void afstore(float* p, float v) {
  __hip_atomic_store(p, v, __ATOMIC_RELAXED, __HIP_MEMORY_SCOPE_AGENT);
}

// ---------------------------------------------------------------- init -----
__global__ __launch_bounds__(1024) void init_k(int* __restrict__ flags) {
  flags[threadIdx.x] = 0;
}

// ---------------------------------------------------------------- mega -----
// (1024, 4): 1 block/CU (already forced by 96KB LDS); VGPR cap 128/wave.
// The streaming worker MLP needs ~106 live -> fits WITHOUT spill.
__global__ __launch_bounds__(1024, 4) void mega_k(
    const float* __restrict__ pos, const float* __restrict__ x,
    const float* __restrict__ W1, const float* __restrict__ b1,
    const float* __restrict__ W2, const float* __restrict__ b2,
    const float* __restrict__ W3, const float* __restrict__ b3,
    float* __restrict__ pout, float* __restrict__ bout,
    float* __restrict__ xout, int* __restrict__ flags)
{
  // 98304B: fps ptab (96KB) / worker cand regions (16 x 512 u64 = 64KB)
  __shared__ __align__(16) float smem[NP * 3];
  __shared__ unsigned long long slt[2][16];
  __shared__ int hist[16];                 // winner idx of rows i-15..i

  const int bid = blockIdx.x;
  const int tid = threadIdx.x;
  const int lane = tid & 63, wid = tid >> 6;

  int b;
  if (bid < BATCH) {
    // ===================== FPS (r2/r6-verified, 16 waves) =================
    b = bid;
    float* const ptab = smem;
    const float* __restrict__ pb = pos + (size_t)b * NP * 3;
    const int base = tid * 8;

    bout[b * MP + tid] = (float)b;
    bout[b * MP + 1024 + tid] = (float)b;

    // load 8 points; stage into LDS table; unpack to registers
    float t[24];
    const float4* __restrict__ pv = (const float4*)(pb + (size_t)tid * 24);
#pragma unroll
    for (int q = 0; q < 6; q++) *(float4*)&t[q * 4] = pv[q];
#pragma unroll
    for (int q = 0; q < 6; q++)
      *(float4*)&ptab[tid * 24 + q * 4] = *(float4*)&t[q * 4];

    v2f px[4], py[4], pz[4], d[4];
#pragma unroll
    for (int j = 0; j < 4; j++) {
      px[j].x = t[6 * j + 0]; py[j].x = t[6 * j + 1]; pz[j].x = t[6 * j + 2];
      px[j].y = t[6 * j + 3]; py[j].y = t[6 * j + 4]; pz[j].y = t[6 * j + 5];
    }

    const float c0x = pb[0], c0y = pb[1], c0z = pb[2];
    if (tid == 0) hist[0] = 0;   // row 0 selects point 0 (flushed later)

    // initial distances to center 0 (same per-element expression as verified)
    float bv = -1.f;
    {
      v2f cx = {c0x, c0x}, cy = {c0y, c0y}, cz = {c0z, c0z};
#pragma unroll
      for (int j = 0; j < 4; j++) {
        v2f dx = px[j] - cx, dy = py[j] - cy, dz = pz[j] - cz;
        v2f nd = dx * dx + dy * dy + dz * dz;
        d[j] = nd;
        bv = fmaxf(bv, fmaxf(nd.x, nd.y));
      }
    }

    for (int i = 1; i < MP; i++) {
      float v = bv;
      DPP_WAVEMAX6(v);
      const float wmax =
          __int_as_float(__builtin_amdgcn_readlane(__float_as_int(v), 63));

      const unsigned long long m = __ballot(bv == wmax);
      const int src = (int)__builtin_ctzll(m);
      const int p = i & 1;
      if (lane == src) {
        int ks = 7;
#pragma unroll
        for (int k = 6; k >= 0; k--) {
          float dv = (k & 1) ? d[k >> 1].y : d[k >> 1].x;
          if (dv == wmax) ks = k;
        }
        slt[p][wid] = ((unsigned long long)__float_as_uint(wmax) << 32)
                      | (unsigned)(base + ks);
      }
      __syncthreads();

      const unsigned long long kv = slt[p][lane & 15];
      const float v2 = __uint_as_float((unsigned)(kv >> 32));
      float v2r = v2;
      DPP_FMAX(v2r, 0x111);
      DPP_FMAX(v2r, 0x112);
      DPP_FMAX(v2r, 0x114);
      DPP_FMAX(v2r, 0x118);
      const float mv =
          __int_as_float(__builtin_amdgcn_readlane(__float_as_int(v2r), 15));
      const unsigned long long m2 = __ballot(v2 == mv);
      const int mw = (int)__builtin_ctzll(m2);
      const int js = __builtin_amdgcn_readlane((int)(unsigned)kv, mw);
      const float ncx = ptab[js * 3 + 0];
      const float ncy = ptab[js * 3 + 1];
      const float ncz = ptab[js * 3 + 2];

      // record winner; batched flush every 16 iters keeps the per-iter loop
      // free of global stores.  Publish lags one window (already drained).
      if (tid == 0) hist[i & 15] = js;
      if ((i & 15) == 15 && wid == 0) {
        asm volatile("s_waitcnt vmcnt(0)" ::: "memory");
        if (lane < 8) astore_i(&flags[(b * 8 + lane) * 16], i - 15);
        if (lane < 16) {
          const int r = i - 15 + lane;           // (r & 15) == lane
          const int jj = hist[lane];
          afstore(&pout[((size_t)b * MP + r) * 3 + 0], ptab[jj * 3 + 0]);
          afstore(&pout[((size_t)b * MP + r) * 3 + 1], ptab[jj * 3 + 1]);
          afstore(&pout[((size_t)b * MP + r) * 3 + 2], ptab[jj * 3 + 2]);
        }
      }

      const v2f cx = {ncx, ncx}, cy = {ncy, ncy}, cz = {ncz, ncz};
      bv = -1.f;
#pragma unroll
      for (int j = 0; j < 4; j++) {
        v2f dx = px[j] - cx, dy = py[j] - cy, dz = pz[j] - cz;
        v2f nd = dx * dx + dy * dy + dz * dz;
        v2f dn;
        dn.x = fminf(d[j].x, nd.x);
        dn.y = fminf(d[j].y, nd.y);
        d[j] = dn;
        bv = fmaxf(bv, fmaxf(dn.x, dn.y));
      }
    }
    if (tid < 8) {     // final publish to all mirrors (last flush drained)
      asm volatile("s_waitcnt vmcnt(0)" ::: "memory");
      astore_i(&flags[(b * 8 + tid) * 16], MP);
    }
    __syncthreads();   // ptab dead; smem becomes worker cand regions
    // fall through: fps waves join the worker pool for their own batch
  } else {
    b = (bid - BATCH) & 3;
  }

  // ======================= WORKERS (168 blocks + 4 fps blocks) ==========
  // Each block polls its own progress MIRROR (8 per batch, 64B-line each).
  // Gap-proportional sleep (production rate ~1 row/us known).
  int* const myprog = &flags[(b * 8 + ((bid >> 2) & 7)) * 16];
  int* const tk     = &flags[512 + b * 16];
  unsigned long long* const cw =
      (unsigned long long*)smem + (size_t)wid * CAND_CAP;
  const float R2 = (float)(0.2 * 0.2);
  const float* __restrict__ pb = pos + (size_t)b * NP * 3;

  for (;;) {
    int t;
    if (lane == 0) t = atomicAdd(tk, 1);
    t = __builtin_amdgcn_readfirstlane(t);
    if (t >= MP) break;
    const int cIdx = t;
    const int wg = b * MP + cIdx;

    for (;;) {
      const int pr = aload(myprog);
      const int g = cIdx + 1 - pr;
      if (g <= 0) break;
      if (g > 128) {
        __builtin_amdgcn_s_sleep(127);
        __builtin_amdgcn_s_sleep(127);
        __builtin_amdgcn_s_sleep(127);
      } else if (g > 16) {
        __builtin_amdgcn_s_sleep(127);
      } else {
        __builtin_amdgcn_s_sleep(16);
      }
    }
    // coords read uncached from the LLC — producer drained its coord
    // stores before publishing (16-row lag).  No fence needed.
    const float cx = afload(&pout[(size_t)wg * 3 + 0]);
    const float cy = afload(&pout[(size_t)wg * 3 + 1]);
    const float cz = afload(&pout[(size_t)wg * 3 + 2]);

    // ---- ball query: compaction (r7-verified) ----
    int cnt = 0;
    for (int basej = 0; basej < NP; basej += 64) {
      const int j = basej + lane;
      float dx = pb[j * 3 + 0] - cx;
      float dy = pb[j * 3 + 1] - cy;
      float dz = pb[j * 3 + 2] - cz;
      float d2 = dx * dx + dy * dy + dz * dz;
      bool in = (d2 <= R2);
      unsigned long long mb = __ballot(in);
      int pre = (int)__popcll(mb & ((1ull << lane) - 1ull));
      int slot = cnt + pre;
      if (in && slot < CAND_CAP)
        cw[slot] = ((unsigned long long)__float_as_uint(d2) << 32)
                   | (unsigned int)j;
      cnt += (int)__popcll(mb);
    }
    if (cnt > CAND_CAP) cnt = CAND_CAP;  // unreachable (max ~360)

    // ---- KNN selection: threshold scan + DPP argmin (r7-verified) ----
    unsigned long long last = 0;
    int myout = -1;
    for (int r = 0; r < KNN; r++) {
      unsigned long long v = ~0ull;
      for (int s = lane; s < cnt; s += 64) {
        const unsigned long long c = cw[s];
        if (c >= last && c < v) v = c;
      }
      const unsigned hi = (unsigned)(v >> 32);
      unsigned h = hi;
      DPP_WAVEMINU6(h);
      const unsigned mhi = (unsigned)__builtin_amdgcn_readlane((int)h, 63);
      const unsigned lo = (hi == mhi) ? (unsigned)v : 0xffffffffu;
      unsigned l2 = lo;
      DPP_WAVEMINU6(l2);
      const unsigned mlo = (unsigned)__builtin_amdgcn_readlane((int)l2, 63);
      if (lane == r) myout = (mhi == 0xffffffffu) ? -1 : (int)mlo;
      last = (mhi == 0xffffffffu)
                 ? ~0ull
                 : ((((unsigned long long)mhi << 32) | mlo) + 1ull);
    }

    // ---- MLP + max: streaming-h2 form, ~106 live regs (fits 128 cap) ----
    const int idx = myout;
    const bool valid = idx >= 0;
    const int j = valid ? idx : 0;
    const float* __restrict__ pj = pos + ((size_t)b * NP + j) * 3;
    const float rx = pj[0] - cx, ry = pj[1] - cy, rz = pj[2] - cz;

    // x @ W1[0:32]: accumulate c ascending (identical chain to old p1_k),
    // W1 rows contiguous -> wide scalar loads.  x row gathered 128B/lane.
    float h1[64];
#pragma unroll
    for (int k = 0; k < 64; k++) h1[k] = 0.f;
    {
      const float* __restrict__ xr = x + ((size_t)b * NP + j) * DIN;
#pragma unroll
      for (int half = 0; half < 2; half++) {
        float xv[16];
#pragma unroll
        for (int q = 0; q < 4; q++)
          *(float4*)&xv[q * 4] = ((const float4*)xr)[half * 4 + q];
#pragma unroll
        for (int c = 0; c < 16; c++) {
          const float xc = xv[c];
          const float* __restrict__ w = W1 + (half * 16 + c) * 64;
#pragma unroll
          for (int k = 0; k < 64; k++) h1[k] += xc * w[k];
        }
      }
    }
#pragma unroll
    for (int k = 0; k < 64; k++) {
      float vv = h1[k] + rx * W1[32 * 64 + k] + ry * W1[33 * 64 + k]
                       + rz * W1[34 * 64 + k] + b1[k];
      h1[k] = fmaxf(vv, 0.f);
    }

    float4 keep = make_float4(0.f, 0.f, 0.f, 0.f);
    for (int pass = 0; pass < 4; pass++) {
      float acc[32];
#pragma unroll
      for (int g = 0; g < 32; g++) acc[g] = b3[pass * 32 + g];
#pragma unroll 2
      for (int c = 0; c < 64; c++) {
        // W2 column c (stride-64 wave-uniform s_loads)
        float a0 = 0.f, a1 = 0.f, a2 = 0.f, a3 = 0.f;
#pragma unroll
        for (int k4 = 0; k4 < 16; k4++) {
          a0 += h1[k4 * 4 + 0] * W2[(k4 * 4 + 0) * 64 + c];
          a1 += h1[k4 * 4 + 1] * W2[(k4 * 4 + 1) * 64 + c];
          a2 += h1[k4 * 4 + 2] * W2[(k4 * 4 + 2) * 64 + c];
          a3 += h1[k4 * 4 + 3] * W2[(k4 * 4 + 3) * 64 + c];
        }
        const float h2c = fmaxf(b2[c] + ((a0 + a1) + (a2 + a3)), 0.f);
        // W3 original [64][128]: row c, channel chunk pass*32..+32 contiguous
        const float* __restrict__ w3r = W3 + c * 128 + pass * 32;
#pragma unroll
        for (int g = 0; g < 32; g++) acc[g] += h2c * w3r[g];
      }
#pragma unroll
      for (int g4 = 0; g4 < 8; g4++) {
        float a0 = valid ? fmaxf(acc[g4 * 4 + 0], 0.f) : 0.f;
        float a1 = valid ? fmaxf(acc[g4 * 4 + 1], 0.f) : 0.f;
        float a2 = valid ? fmaxf(acc[g4 * 4 + 2], 0.f) : 0.f;
        float a3 = valid ? fmaxf(acc[g4 * 4 + 3], 0.f) : 0.f;
        DPP_WAVEMAX6(a0);
        DPP_WAVEMAX6(a1);
        DPP_WAVEMAX6(a2);
        DPP_WAVEMAX6(a3);
        const float m0 =
            __int_as_float(__builtin_amdgcn_readlane(__float_as_int(a0), 63));
        const float m1 =
            __int_as_float(__builtin_amdgcn_readlane(__float_as_int(a1), 63));
        const float m2 =
            __int_as_float(__builtin_amdgcn_readlane(__float_as_int(a2), 63));
        const float m3 =
            __int_as_float(__builtin_amdgcn_readlane(__float_as_int(a3), 63));
        if (lane == pass * 8 + g4) {
          keep.x = m0; keep.y = m1; keep.z = m2; keep.w = m3;
        }
      }
    }
    if (lane < 32)
      *(float4*)&xout[(size_t)wg * 128 + lane * 4] = keep;
  }
}

// --------------------------------------------------------------- launch ----
extern "C" void kernel_launch(void* const* d_in, const int* in_sizes, int n_in,
                              void* d_out, int out_size, void* d_ws, size_t ws_size,
                              hipStream_t stream)
{
  const float* x   = (const float*)d_in[0];
  const float* pos = (const float*)d_in[1];
  // d_in[2] = batch (unused; layout is implicit)
  const float* W1 = (const float*)d_in[3];
  const float* b1 = (const float*)d_in[4];
  const float* W2 = (const float*)d_in[5];
  const float* b2 = (const float*)d_in[6];
  const float* W3 = (const float*)d_in[7];
  const float* b3 = (const float*)d_in[8];

  float* out  = (float*)d_out;
  float* xout = out;                          // 8192*128
  float* pout = out + 8192 * 128;             // 8192*3
  float* bout = out + 8192 * 128 + 8192 * 3;  // 8192

  int* flags = (int*)d_ws;                    // 1024 ints

  init_k<<<dim3(1), dim3(1024), 0, stream>>>(flags);
  mega_k<<<dim3(NBLK), dim3(1024), 0, stream>>>(pos, x, W1, b1, W2, b2, W3,
                                                b3, pout, bout, xout, flags);
}